// Round 5
// baseline (291.342 us; speedup 1.0000x reference)
//
#include <hip/hip_runtime.h>
#include <hip/hip_cooperative_groups.h>

namespace cg = cooperative_groups;

#define BATCH 128
#define NC1   1152
#define ND1   8
#define NC2   10
#define ND2   16
#define HALFC (NC1 / 2)      // 576 capsules per block
#define SDIM  (NC2 * ND2)    // 160
#define NGRP  32             // 16-lane groups per 512-thread block
#define CPG   (HALFC / NGRP) // 18 capsules per group
#define NWAVE 8              // waves per block

__device__ __forceinline__ unsigned pack_bf16(float a, float b) {
    unsigned ua = __float_as_uint(a), ub = __float_as_uint(b);
    ua = (ua + 0x7FFFu + ((ua >> 16) & 1u)) >> 16;
    ub = (ub + 0x7FFFu + ((ub >> 16) & 1u)) >> 16;
    return ua | (ub << 16);
}
__device__ __forceinline__ float2 unpack_bf16(unsigned v) {
    float2 f;
    f.x = __uint_as_float(v << 16);
    f.y = __uint_as_float(v & 0xFFFF0000u);
    return f;
}

// Grid = 256 blocks (PROVEN cooperative-launch envelope from rounds 2-3):
// block (b, h): batch b = blk>>1, capsule half h = blk&1.
// 512 threads = 32 groups x 16 lanes; group owns 18 capsules; lane = d (D2).
// u_hat computed ONCE (single W stream), kept bf16-packed in 90 VGPRs/thread;
// routing passes 1-2 run from registers. __launch_bounds__(512,2) -> VGPR cap
// 256: no spill (round-3 failure: 1024-thr block capped at 64 VGPR -> 254 MB
// scratch traffic). Round-4 failure: 512-block coop grid refused to launch.
__global__ __launch_bounds__(512, 2) void caps_routing_h(
    const float* __restrict__ x,     // [B, C1*D1]
    const float* __restrict__ W,     // [C1, C2, D2, D1]
    const float* __restrict__ bias,  // [C2*D2]
    float* __restrict__ out,         // [B, C2*D2]
    float* __restrict__ spart)       // [B][2][SDIM] partials (160 KB)
{
    const int blk  = blockIdx.x;
    const int b    = blk >> 1;
    const int h    = blk & 1;
    const int tid  = threadIdx.x;
    const int grp  = tid >> 4;   // 0..31
    const int d    = tid & 15;   // D2 lane
    const int wave = tid >> 6;   // 0..7

    __shared__ float prim[HALFC][ND1];     // 18 KB
    __shared__ float sred[NWAVE][SDIM];    // 5 KB
    __shared__ float vbuf[SDIM];           // 640 B

    const float* xb = x + (size_t)b * (NC1 * ND1) + (size_t)h * (HALFC * ND1);

    // ---- PrimaryCaps squash for this block's capsule half ----
    for (int c = tid; c < HALFC; c += 512) {
        float4 a0 = *(const float4*)(xb + c * 8);
        float4 a1 = *(const float4*)(xb + c * 8 + 4);
        float sq = a0.x*a0.x + a0.y*a0.y + a0.z*a0.z + a0.w*a0.w
                 + a1.x*a1.x + a1.y*a1.y + a1.z*a1.z + a1.w*a1.w;
        float g = (sq / (1.0f + sq)) * rsqrtf(sq + 1e-8f);
        prim[c][0] = a0.x * g; prim[c][1] = a0.y * g;
        prim[c][2] = a0.z * g; prim[c][3] = a0.w * g;
        prim[c][4] = a1.x * g; prim[c][5] = a1.y * g;
        prim[c][6] = a1.z * g; prim[c][7] = a1.w * g;
    }
    __syncthreads();

    cg::grid_group grid = cg::this_grid();

    unsigned u2[CPG][5];  // bf16x2-packed u_hat: 18 caps x 10 j = 90 VGPRs
    float sp[NC2];
    float vsum[NC2];

    #pragma unroll
    for (int j = 0; j < NC2; ++j) sp[j] = 0.0f;

    // ---- Single W stream: compute u_hat, keep in regs, accumulate pass-0 s.
    // Rotate capsule order by b%18 to decorrelate same-XCD L2 streams.
    const int rot = b % CPG;
    #pragma unroll
    for (int i = 0; i < CPG; ++i) {
        int r = i + rot; if (r >= CPG) r -= CPG;
        const int cl = grp + (r << 5);
        float p[8];
        #pragma unroll
        for (int k = 0; k < 8; ++k) p[k] = prim[cl][k];

        const float* Wc = W + (size_t)(h * HALFC + cl) * (NC2 * ND2 * ND1) + d * ND1;
        float u[NC2];
        #pragma unroll
        for (int j = 0; j < NC2; ++j) {
            const float4 w0 = *(const float4*)(Wc + j * (ND2 * ND1));
            const float4 w1 = *(const float4*)(Wc + j * (ND2 * ND1) + 4);
            u[j] = w0.x*p[0] + w0.y*p[1] + w0.z*p[2] + w0.w*p[3]
                 + w1.x*p[4] + w1.y*p[5] + w1.z*p[6] + w1.w*p[7];
            sp[j] += u[j];
        }
        #pragma unroll
        for (int qq = 0; qq < 5; ++qq) u2[i][qq] = pack_bf16(u[2*qq], u[2*qq+1]);
    }

    for (int pass = 0; pass < 3; ++pass) {
        if (pass > 0) {
            // ---- routing pass from registers ----
            #pragma unroll
            for (int j = 0; j < NC2; ++j) sp[j] = 0.0f;
            #pragma unroll
            for (int i = 0; i < CPG; ++i) {
                float u[NC2];
                #pragma unroll
                for (int qq = 0; qq < 5; ++qq) {
                    float2 f = unpack_bf16(u2[i][qq]);
                    u[2*qq] = f.x; u[2*qq+1] = f.y;
                }
                float r[NC2];
                #pragma unroll
                for (int j = 0; j < NC2; ++j) {
                    float t = u[j] * vsum[j];
                    t += __shfl_xor(t, 1);
                    t += __shfl_xor(t, 2);
                    t += __shfl_xor(t, 4);
                    t += __shfl_xor(t, 8);
                    r[j] = t;
                }
                float m = r[0];
                #pragma unroll
                for (int j = 1; j < NC2; ++j) m = fmaxf(m, r[j]);
                float ssum = 0.0f;
                #pragma unroll
                for (int j = 0; j < NC2; ++j) { r[j] = __expf(r[j] - m); ssum += r[j]; }
                float inv = 1.0f / ssum;
                #pragma unroll
                for (int j = 0; j < NC2; ++j) sp[j] += (r[j] * inv) * u[j];
            }
        }

        // ---- reduce s over 32 groups: intra-wave shfl, then LDS over 8 waves ----
        #pragma unroll
        for (int j = 0; j < NC2; ++j) {
            sp[j] += __shfl_xor(sp[j], 16);
            sp[j] += __shfl_xor(sp[j], 32);
        }
        if ((tid & 63) < 16) {
            #pragma unroll
            for (int j = 0; j < NC2; ++j) sred[wave][j * 16 + d] = sp[j];
        }
        __syncthreads();

        // ---- write this half's partial s to workspace ----
        if (tid < SDIM) {
            float acc = 0.0f;
            #pragma unroll
            for (int w = 0; w < NWAVE; ++w) acc += sred[w][tid];
            spart[(size_t)(b * 2 + h) * SDIM + tid] = acc;
        }

        grid.sync();   // all partials visible

        // ---- combine halves, bias, squash -> v (redundant per pair) ----
        if (tid < SDIM) {
            float acc = spart[(size_t)(b * 2 + 0) * SDIM + tid]
                      + spart[(size_t)(b * 2 + 1) * SDIM + tid];
            float s = bias[tid] + (pass == 0 ? 0.1f * acc : acc);
            float sq = s * s;
            sq += __shfl_xor(sq, 1);
            sq += __shfl_xor(sq, 2);
            sq += __shfl_xor(sq, 4);
            sq += __shfl_xor(sq, 8);
            float vv = (sq / (1.0f + sq)) * rsqrtf(sq + 1e-8f) * s;
            if (pass == 2) {
                if (h == 0) out[(size_t)b * SDIM + tid] = vv;
            } else {
                vbuf[tid] = vv;
            }
        }
        __syncthreads();

        if (pass < 2) {
            #pragma unroll
            for (int j = 0; j < NC2; ++j) {
                float vv = vbuf[j * 16 + d];
                vsum[j] = (pass == 0) ? vv : (vsum[j] + vv);
            }
            grid.sync();   // spart reads done before next pass overwrites
        }
    }
}

extern "C" void kernel_launch(void* const* d_in, const int* in_sizes, int n_in,
                              void* d_out, int out_size, void* d_ws, size_t ws_size,
                              hipStream_t stream) {
    const float* x    = (const float*)d_in[0];  // [128, 9216]
    const float* W    = (const float*)d_in[1];  // [1152, 10, 16, 8]
    const float* bias = (const float*)d_in[2];  // [1, 1, 10, 16]
    float* out   = (float*)d_out;               // [128, 1, 10, 16, 1]
    float* spart = (float*)d_ws;                // 128*2*160 floats = 160 KB

    void* args[] = {(void*)&x, (void*)&W, (void*)&bias, (void*)&out, (void*)&spart};
    hipLaunchCooperativeKernel((const void*)caps_routing_h,
                               dim3(BATCH * 2), dim3(512), args, 0, stream);
}

// Round 6
// 107.644 us; speedup vs baseline: 2.7065x; 2.7065x over previous
//
#include <hip/hip_runtime.h>

#define BATCH 128
#define NC1   1152
#define ND1   8
#define NC2   10
#define ND2   16
#define SDIM  (NC2 * ND2)    // 160

// ---- kernel B tiling ----
#define CB 16                // caps per block
#define BB 32                // batch per block
// grid = (1152/16, 128/32) = (72, 4) = 288 blocks

// ---- kernel C ----
#define NGRP 32              // 16-lane groups per 512-thread block
#define CPGC (NC1 / NGRP)    // 36 caps per group

__device__ __forceinline__ unsigned pack_bf16(float a, float b) {
    unsigned ua = __float_as_uint(a), ub = __float_as_uint(b);
    ua = (ua + 0x7FFFu + ((ua >> 16) & 1u)) >> 16;
    ub = (ub + 0x7FFFu + ((ub >> 16) & 1u)) >> 16;
    return ua | (ub << 16);
}
__device__ __forceinline__ float2 unpack_bf16(unsigned v) {
    float2 f;
    f.x = __uint_as_float(v << 16);
    f.y = __uint_as_float(v & 0xFFFF0000u);
    return f;
}

// =================== Kernel B: u_hat = W @ squash(x), bf16 to ws ===========
// Thread (cl, d) keeps W[c, :, d, :] (80 f32) in registers, loops 32 batch
// elements. u_ws layout: uint bf16x2 [b][c][jp(0..4)][d(0..15)] -> every
// load/store is 16 consecutive dwords per 16-lane group.
__global__ __launch_bounds__(256, 1) void caps_uhat(
    const float* __restrict__ x,     // [B, C1*D1]
    const float* __restrict__ W,     // [C1, C2, D2, D1]
    unsigned* __restrict__ u_ws)     // [B][C1][5][16]
{
    const int cb  = blockIdx.x;      // c-chunk 0..71
    const int bb  = blockIdx.y;      // b-chunk 0..3
    const int tid = threadIdx.x;
    const int cl  = tid >> 4;        // 0..15 local capsule
    const int d   = tid & 15;        // D2 index

    __shared__ float prim[BB][CB][ND1];  // 16 KB

    // load + squash the (32 b x 16 c) prim tile
    for (int i = tid; i < BB * CB; i += 256) {
        const int b = i >> 4, c = i & 15;
        const float* xr = x + ((size_t)(bb * BB + b) * NC1 + (cb * CB + c)) * ND1;
        float4 a0 = *(const float4*)(xr);
        float4 a1 = *(const float4*)(xr + 4);
        float sq = a0.x*a0.x + a0.y*a0.y + a0.z*a0.z + a0.w*a0.w
                 + a1.x*a1.x + a1.y*a1.y + a1.z*a1.z + a1.w*a1.w;
        float g = (sq / (1.0f + sq)) * rsqrtf(sq + 1e-8f);
        prim[b][c][0] = a0.x * g; prim[b][c][1] = a0.y * g;
        prim[b][c][2] = a0.z * g; prim[b][c][3] = a0.w * g;
        prim[b][c][4] = a1.x * g; prim[b][c][5] = a1.y * g;
        prim[b][c][6] = a1.z * g; prim[b][c][7] = a1.w * g;
    }
    __syncthreads();

    // W[c, j, d, k] for this thread's (c, d): 10 j x 8 k = 80 VGPRs
    const int c_glob = cb * CB + cl;
    float w[NC2][ND1];
    #pragma unroll
    for (int j = 0; j < NC2; ++j) {
        const float* Wr = W + (((size_t)c_glob * NC2 + j) * ND2 + d) * ND1;
        float4 w0 = *(const float4*)(Wr);
        float4 w1 = *(const float4*)(Wr + 4);
        w[j][0] = w0.x; w[j][1] = w0.y; w[j][2] = w0.z; w[j][3] = w0.w;
        w[j][4] = w1.x; w[j][5] = w1.y; w[j][6] = w1.z; w[j][7] = w1.w;
    }

    for (int b = 0; b < BB; ++b) {
        float p[ND1];
        #pragma unroll
        for (int k = 0; k < ND1; ++k) p[k] = prim[b][cl][k];  // LDS broadcast

        unsigned* ur = u_ws + (((size_t)(bb * BB + b) * NC1 + c_glob) * 5) * 16 + d;
        #pragma unroll
        for (int jp = 0; jp < 5; ++jp) {
            float u0 = 0.f, u1 = 0.f;
            #pragma unroll
            for (int k = 0; k < ND1; ++k) {
                u0 += w[2*jp  ][k] * p[k];
                u1 += w[2*jp+1][k] * p[k];
            }
            ur[jp * 16] = pack_bf16(u0, u1);
        }
    }
}

// =================== Kernel C: 3 routing passes from u_ws ==================
// Block = one batch element. 512 threads = 32 groups x 16 lanes (lane = d).
// Group owns 36 capsules; all reduction over c is in-block. No grid sync.
__global__ __launch_bounds__(512, 1) void caps_route(
    const unsigned* __restrict__ u_ws,  // [B][C1][5][16]
    const float* __restrict__ bias,     // [SDIM]
    float* __restrict__ out)            // [B][SDIM]
{
    const int b    = blockIdx.x;
    const int tid  = threadIdx.x;
    const int grp  = tid >> 4;   // 0..31
    const int d    = tid & 15;
    const int wave = tid >> 6;   // 0..7

    __shared__ float sred[8][SDIM];   // 5 KB
    __shared__ float vbuf[SDIM];      // 640 B

    const unsigned* ub = u_ws + (size_t)b * NC1 * 5 * 16 + d;

    float vsum[NC2];
    float sp[NC2];

    for (int pass = 0; pass < 3; ++pass) {
        #pragma unroll
        for (int j = 0; j < NC2; ++j) sp[j] = 0.0f;

        // prefetch first capsule's 5 dwords
        unsigned o[5];
        {
            const unsigned* uc = ub + (size_t)grp * 80;
            #pragma unroll
            for (int jp = 0; jp < 5; ++jp) o[jp] = uc[jp * 16];
        }

        for (int i = 0; i < CPGC; ++i) {
            unsigned on[5];
            if (i + 1 < CPGC) {
                const unsigned* uc = ub + (size_t)(grp + ((i + 1) << 5)) * 80;
                #pragma unroll
                for (int jp = 0; jp < 5; ++jp) on[jp] = uc[jp * 16];
            }

            float u[NC2];
            #pragma unroll
            for (int jp = 0; jp < 5; ++jp) {
                float2 f = unpack_bf16(o[jp]);
                u[2*jp] = f.x; u[2*jp+1] = f.y;
            }

            if (pass == 0) {
                #pragma unroll
                for (int j = 0; j < NC2; ++j) sp[j] += u[j];
            } else {
                float r[NC2];
                #pragma unroll
                for (int j = 0; j < NC2; ++j) {
                    float t = u[j] * vsum[j];
                    t += __shfl_xor(t, 1);
                    t += __shfl_xor(t, 2);
                    t += __shfl_xor(t, 4);
                    t += __shfl_xor(t, 8);
                    r[j] = t;
                }
                float m = r[0];
                #pragma unroll
                for (int j = 1; j < NC2; ++j) m = fmaxf(m, r[j]);
                float ssum = 0.0f;
                #pragma unroll
                for (int j = 0; j < NC2; ++j) { r[j] = __expf(r[j] - m); ssum += r[j]; }
                float inv = 1.0f / ssum;
                #pragma unroll
                for (int j = 0; j < NC2; ++j) sp[j] += (r[j] * inv) * u[j];
            }

            #pragma unroll
            for (int jp = 0; jp < 5; ++jp) o[jp] = on[jp];
        }

        // reduce over 32 groups: shfl within wave, LDS across 8 waves
        #pragma unroll
        for (int j = 0; j < NC2; ++j) {
            sp[j] += __shfl_xor(sp[j], 16);
            sp[j] += __shfl_xor(sp[j], 32);
        }
        if ((tid & 63) < 16) {
            #pragma unroll
            for (int j = 0; j < NC2; ++j) sred[wave][j * 16 + d] = sp[j];
        }
        __syncthreads();

        // final s, bias, squash -> v
        if (tid < SDIM) {
            float acc = 0.0f;
            #pragma unroll
            for (int w = 0; w < 8; ++w) acc += sred[w][tid];
            float s = bias[tid] + (pass == 0 ? 0.1f * acc : acc);
            float sq = s * s;
            sq += __shfl_xor(sq, 1);
            sq += __shfl_xor(sq, 2);
            sq += __shfl_xor(sq, 4);
            sq += __shfl_xor(sq, 8);
            float vv = (sq / (1.0f + sq)) * rsqrtf(sq + 1e-8f) * s;
            if (pass == 2) out[(size_t)b * SDIM + tid] = vv;
            else           vbuf[tid] = vv;
        }
        __syncthreads();

        if (pass < 2) {
            #pragma unroll
            for (int j = 0; j < NC2; ++j) {
                float vv = vbuf[j * 16 + d];
                vsum[j] = (pass == 0) ? vv : (vsum[j] + vv);
            }
        }
        __syncthreads();  // protect sred/vbuf reuse next pass
    }
}

// =================== Fallback: round-1 fused kernel (proven, 198 us) =======
__global__ __launch_bounds__(1024) void caps_fused(
    const float* __restrict__ x, const float* __restrict__ W,
    const float* __restrict__ bias, float* __restrict__ out)
{
    const int b    = blockIdx.x;
    const int tid  = threadIdx.x;
    const int grp  = tid >> 4;
    const int d    = tid & 15;
    const int wave = tid >> 6;
    const int lane = tid & 63;

    __shared__ float prim[NC1][ND1];
    __shared__ float sred[16][SDIM];
    __shared__ float vbuf[SDIM];

    const float* xb = x + (size_t)b * (NC1 * ND1);
    for (int c = tid; c < NC1; c += 1024) {
        float4 a0 = *(const float4*)(xb + c * 8);
        float4 a1 = *(const float4*)(xb + c * 8 + 4);
        float sq = a0.x*a0.x + a0.y*a0.y + a0.z*a0.z + a0.w*a0.w
                 + a1.x*a1.x + a1.y*a1.y + a1.z*a1.z + a1.w*a1.w;
        float g = (sq / (1.0f + sq)) * rsqrtf(sq + 1e-8f);
        prim[c][0] = a0.x * g; prim[c][1] = a0.y * g;
        prim[c][2] = a0.z * g; prim[c][3] = a0.w * g;
        prim[c][4] = a1.x * g; prim[c][5] = a1.y * g;
        prim[c][6] = a1.z * g; prim[c][7] = a1.w * g;
    }
    __syncthreads();

    float vsum[NC2], sp[NC2];
    for (int pass = 0; pass < 3; ++pass) {
        #pragma unroll
        for (int j = 0; j < NC2; ++j) sp[j] = 0.0f;
        for (int c = grp; c < NC1; c += 64) {
            float p[8];
            #pragma unroll
            for (int k = 0; k < 8; ++k) p[k] = prim[c][k];
            const float* Wc = W + (size_t)c * (NC2 * ND2 * ND1) + d * ND1;
            float u[NC2];
            #pragma unroll
            for (int j = 0; j < NC2; ++j) {
                const float4 w0 = *(const float4*)(Wc + j * (ND2 * ND1));
                const float4 w1 = *(const float4*)(Wc + j * (ND2 * ND1) + 4);
                u[j] = w0.x*p[0] + w0.y*p[1] + w0.z*p[2] + w0.w*p[3]
                     + w1.x*p[4] + w1.y*p[5] + w1.z*p[6] + w1.w*p[7];
            }
            if (pass == 0) {
                #pragma unroll
                for (int j = 0; j < NC2; ++j) sp[j] += u[j];
            } else {
                float r[NC2];
                #pragma unroll
                for (int j = 0; j < NC2; ++j) {
                    float t = u[j] * vsum[j];
                    t += __shfl_xor(t, 1); t += __shfl_xor(t, 2);
                    t += __shfl_xor(t, 4); t += __shfl_xor(t, 8);
                    r[j] = t;
                }
                float m = r[0];
                #pragma unroll
                for (int j = 1; j < NC2; ++j) m = fmaxf(m, r[j]);
                float ssum = 0.0f;
                #pragma unroll
                for (int j = 0; j < NC2; ++j) { r[j] = __expf(r[j] - m); ssum += r[j]; }
                float inv = 1.0f / ssum;
                #pragma unroll
                for (int j = 0; j < NC2; ++j) sp[j] += (r[j] * inv) * u[j];
            }
        }
        #pragma unroll
        for (int j = 0; j < NC2; ++j) {
            sp[j] += __shfl_xor(sp[j], 16);
            sp[j] += __shfl_xor(sp[j], 32);
        }
        if (lane < 16) {
            #pragma unroll
            for (int j = 0; j < NC2; ++j) sred[wave][j * 16 + d] = sp[j];
        }
        __syncthreads();
        if (tid < SDIM) {
            float acc = 0.0f;
            #pragma unroll
            for (int w = 0; w < 16; ++w) acc += sred[w][tid];
            float s = bias[tid] + (pass == 0 ? 0.1f * acc : acc);
            float sq = s * s;
            sq += __shfl_xor(sq, 1); sq += __shfl_xor(sq, 2);
            sq += __shfl_xor(sq, 4); sq += __shfl_xor(sq, 8);
            float vv = (sq / (1.0f + sq)) * rsqrtf(sq + 1e-8f) * s;
            if (pass == 2) out[(size_t)b * SDIM + tid] = vv;
            else           vbuf[tid] = vv;
        }
        __syncthreads();
        if (pass < 2) {
            #pragma unroll
            for (int j = 0; j < NC2; ++j) {
                float vv = vbuf[j * 16 + d];
                vsum[j] = (pass == 0) ? vv : (vsum[j] + vv);
            }
        }
        __syncthreads();
    }
}

extern "C" void kernel_launch(void* const* d_in, const int* in_sizes, int n_in,
                              void* d_out, int out_size, void* d_ws, size_t ws_size,
                              hipStream_t stream) {
    const float* x    = (const float*)d_in[0];  // [128, 9216]
    const float* W    = (const float*)d_in[1];  // [1152, 10, 16, 8]
    const float* bias = (const float*)d_in[2];  // [1, 1, 10, 16]
    float* out = (float*)d_out;                 // [128, 1, 10, 16, 1]

    const size_t need = (size_t)BATCH * NC1 * 5 * 16 * sizeof(unsigned);  // 47.2 MB
    if (ws_size >= need) {
        unsigned* u_ws = (unsigned*)d_ws;
        caps_uhat <<<dim3(NC1 / CB, BATCH / BB), 256, 0, stream>>>(x, W, u_ws);
        caps_route<<<BATCH, 512, 0, stream>>>(u_ws, bias, out);
    } else {
        caps_fused<<<BATCH, 1024, 0, stream>>>(x, W, bias, out);
    }
}